// Round 1
// baseline (1596.150 us; speedup 1.0000x reference)
//
#include <hip/hip_runtime.h>
#include <hip/hip_bf16.h>

namespace {

constexpr int NN = 30000;   // nodes
constexpr int NE = 60000;   // edges
constexpr int NB = 1200;    // graphs
constexpr int MD = 64;      // DIM
constexpr int FE = 14;      // FEAT
constexpr int PG = 25;      // nodes per graph
constexpr int KH = 128;     // edge-MLP hidden width

typedef __attribute__((ext_vector_type(8))) __bf16 bf16x8;
typedef __attribute__((ext_vector_type(4))) float f32x4;

__device__ __forceinline__ float sigf(float x) { return 1.0f / (1.0f + expf(-x)); }

// ---------------- lin0: node_h = relu(x @ W_lin0.T + b) ----------------
__global__ __launch_bounds__(256) void k_lin0(const float* __restrict__ x,
    const float* __restrict__ W, const float* __restrict__ b,
    float* __restrict__ node_h)
{
  __shared__ float xs[4][FE];
  int tid = threadIdx.x, nl = tid >> 6, d = tid & 63;
  int n = blockIdx.x * 4 + nl;
  if (d < FE) xs[nl][d] = x[n * FE + d];
  __syncthreads();
  float a = b[d];
#pragma unroll
  for (int f = 0; f < FE; ++f) a += xs[nl][f] * W[d * FE + f];
  node_h[n * MD + d] = fmaxf(a, 0.0f);
}

// ---------------- h1 = relu(edge_attr @ W_h1.T + b) -> bf16 ----------------
__global__ __launch_bounds__(256) void k_h1(const float* __restrict__ ea,
    const float* __restrict__ W, const float* __restrict__ b,
    __hip_bfloat16* __restrict__ h1)
{
  int gid = blockIdx.x * 256 + threadIdx.x;   // e*128 + k
  int e = gid >> 7, k = gid & 127;
  const float* a = ea + e * 4;
  float v = b[k] + a[0] * W[k * 4 + 0] + a[1] * W[k * 4 + 1]
                 + a[2] * W[k * 4 + 2] + a[3] * W[k * 4 + 3];
  h1[gid] = __float2bfloat16(fmaxf(v, 0.0f));
}

// ------------- pack W_h2 into MFMA B-fragment order (bf16) -------------
// frag(i, ks, ot): B[k][n] with n = ot*16 + (lane&15), k = ks*32 + (lane>>4)*8 + j
// index = (((i*4+ks)*4+ot)*64 + lane)*8 + j
__global__ __launch_bounds__(256) void k_pack_b(const float* __restrict__ W_h2,
    __hip_bfloat16* __restrict__ bpre)
{
  int tid = blockIdx.x * 256 + threadIdx.x;   // < 64*4*4*64*8 = 524288
  int j = tid & 7;
  int l = (tid >> 3) & 63;
  int ot = (tid >> 9) & 3;
  int ks = (tid >> 11) & 3;
  int i = tid >> 13;
  int row = i * MD + ot * 16 + (l & 15);      // W_h2 row = i*64 + o
  int col = ks * 32 + (l >> 4) * 8 + j;       // W_h2 col = k
  bpre[tid] = __float2bfloat16(W_h2[row * KH + col]);
}

// ---------------- degree ----------------
__global__ __launch_bounds__(256) void k_deg(const int* __restrict__ tgt, int* __restrict__ cnt)
{
  int e = blockIdx.x * 256 + threadIdx.x;
  if (e < NE) atomicAdd(&cnt[tgt[e]], 1);
}
__global__ __launch_bounds__(256) void k_invdeg(const int* __restrict__ cnt, float* __restrict__ inv)
{
  int n = blockIdx.x * 256 + threadIdx.x;
  if (n < NN) inv[n] = 1.0f / fmaxf((float)cnt[n], 1.0f);
}

// ------------- sx[t,:] += node_h[src_e,:] for each edge e->t -------------
__global__ __launch_bounds__(256) void k_sx(const int* __restrict__ src,
    const int* __restrict__ tgt, const float* __restrict__ node_h,
    float* __restrict__ sx)
{
  int gid = blockIdx.x * 256 + threadIdx.x;   // e*64 + d
  int e = gid >> 6, d = gid & 63;
  atomicAdd(&sx[tgt[e] * MD + d], node_h[src[e] * MD + d]);
}

// ------------- message kernel: C[e,o] = sum_i x_e[i] * (h1_e . W_h2[i*64+o,:])
// scatter-added into aggr[tgt[e], o]. 4 waves/block, 32 edges/wave.
__global__ __launch_bounds__(256) void k_msg(
    const __hip_bfloat16* __restrict__ h1,
    const __hip_bfloat16* __restrict__ bpre,
    const float* __restrict__ node_h,
    const int* __restrict__ src,
    const int* __restrict__ tgt,
    float* __restrict__ aggr)
{
  __shared__ float x_lds[128 * 65];   // stride 65 to break bank conflicts
  __shared__ int s_src[128];
  __shared__ int s_tgt[128];
  const int tid = threadIdx.x;
  const int wid = tid >> 6;
  const int lane = tid & 63;
  const int eb0 = blockIdx.x * 128;

  if (tid < 128) {
    int ge = eb0 + tid;
    s_src[tid] = (ge < NE) ? src[ge] : -1;
    s_tgt[tid] = (ge < NE) ? tgt[ge] : -1;
  }
  __syncthreads();
  for (int idx = tid; idx < 128 * MD; idx += 256) {
    int el = idx >> 6, d = idx & 63;
    int s = s_src[el];
    x_lds[el * 65 + d] = (s >= 0) ? node_h[s * MD + d] : 0.0f;
  }

  // A fragments: h1 rows (edges). lane: row = lane&15, k = ks*32 + (lane>>4)*8 + j
  const int ew = wid * 32;
  bf16x8 af[2][4];
#pragma unroll
  for (int m = 0; m < 2; ++m) {
    int ge = eb0 + ew + m * 16 + (lane & 15);
    if (ge >= NE) ge = 0;                      // x_lds row is 0 for OOB -> C row = 0
    const bf16x8* ap = reinterpret_cast<const bf16x8*>(h1 + (size_t)ge * KH);
#pragma unroll
    for (int ks = 0; ks < 4; ++ks)
      af[m][ks] = ap[ks * 4 + (lane >> 4)];
  }
  __syncthreads();

  const f32x4 z4 = {0.0f, 0.0f, 0.0f, 0.0f};
  f32x4 c[2][4];
#pragma unroll
  for (int m = 0; m < 2; ++m)
#pragma unroll
    for (int ot = 0; ot < 4; ++ot) c[m][ot] = z4;

  const bf16x8* bp = reinterpret_cast<const bf16x8*>(bpre) + lane;

  for (int i = 0; i < MD; ++i) {
    f32x4 g[2][4];
#pragma unroll
    for (int ks = 0; ks < 4; ++ks) {
      bf16x8 bfr[4];
#pragma unroll
      for (int ot = 0; ot < 4; ++ot)
        bfr[ot] = bp[(((i * 4 + ks) * 4 + ot) << 6)];
#pragma unroll
      for (int ot = 0; ot < 4; ++ot)
#pragma unroll
        for (int m = 0; m < 2; ++m)
          g[m][ot] = __builtin_amdgcn_mfma_f32_16x16x32_bf16(
              af[m][ks], bfr[ot], (ks == 0) ? z4 : g[m][ot], 0, 0, 0);
    }
    // C += x_e[i] * G_i   (x in f32; C/D layout: col=lane&15, row=(lane>>4)*4+r)
#pragma unroll
    for (int m = 0; m < 2; ++m) {
      float xv[4];
#pragma unroll
      for (int r = 0; r < 4; ++r)
        xv[r] = x_lds[(ew + m * 16 + (lane >> 4) * 4 + r) * 65 + i];
#pragma unroll
      for (int ot = 0; ot < 4; ++ot)
#pragma unroll
        for (int r = 0; r < 4; ++r)
          c[m][ot][r] += xv[r] * g[m][ot][r];
    }
  }

  // scatter into aggr[tgt]
#pragma unroll
  for (int m = 0; m < 2; ++m)
#pragma unroll
    for (int r = 0; r < 4; ++r) {
      int el = ew + m * 16 + (lane >> 4) * 4 + r;
      int t = s_tgt[el];
      if (t >= 0) {
#pragma unroll
        for (int ot = 0; ot < 4; ++ot)
          atomicAdd(&aggr[t * MD + ot * 16 + (lane & 15)], c[m][ot][r]);
      }
    }
}

// ------------- fused NNConv epilogue + GRU cell (4 nodes/block) -------------
__global__ __launch_bounds__(256) void k_gru(
    float* __restrict__ node_h,
    const float* __restrict__ aggr, const float* __restrict__ sx,
    const float* __restrict__ inv_deg,
    const float* __restrict__ W_root, const float* __restrict__ b_conv,
    const float* __restrict__ b_h2,
    const float* __restrict__ W_ih, const float* __restrict__ W_hh,
    const float* __restrict__ b_ih, const float* __restrict__ b_hh)
{
  __shared__ float h_s[4][64], sx_s[4][64], m_s[4][64];
  int tid = threadIdx.x, nl = tid >> 6, d = tid & 63;
  int n = blockIdx.x * 4 + nl;
  float hv = node_h[n * MD + d];
  h_s[nl][d] = hv;
  sx_s[nl][d] = sx[n * MD + d];
  __syncthreads();
  // aggr mean incl. b_h2 bias term: (msg_sum + sx @ B2) * inv_deg
  float acc = aggr[n * MD + d];
  for (int i = 0; i < 64; ++i) acc += sx_s[nl][i] * b_h2[i * MD + d];
  acc *= inv_deg[n];
  float mr = acc + b_conv[d];
  for (int i = 0; i < 64; ++i) mr += h_s[nl][i] * W_root[i * MD + d];
  float mv = fmaxf(mr, 0.0f);
  m_s[nl][d] = mv;
  __syncthreads();
  float gir = b_ih[d], giz = b_ih[64 + d], gin = b_ih[128 + d];
  for (int j = 0; j < 64; ++j) {
    float mj = m_s[nl][j];
    gir += mj * W_ih[d * 64 + j];
    giz += mj * W_ih[(64 + d) * 64 + j];
    gin += mj * W_ih[(128 + d) * 64 + j];
  }
  float ghr = b_hh[d], ghz = b_hh[64 + d], ghn = b_hh[128 + d];
  for (int j = 0; j < 64; ++j) {
    float hj = h_s[nl][j];
    ghr += hj * W_hh[d * 64 + j];
    ghz += hj * W_hh[(64 + d) * 64 + j];
    ghn += hj * W_hh[(128 + d) * 64 + j];
  }
  float r = sigf(gir + ghr), z = sigf(giz + ghz);
  float nv = tanhf(gin + r * ghn);
  node_h[n * MD + d] = (1.0f - z) * nv + z * hv;
}

// ------------- Set2Set LSTM cell (1 graph / 64-thread wave) -------------
__global__ __launch_bounds__(64) void k_lstm(const float* __restrict__ q_star,
    float* __restrict__ hl, float* __restrict__ cl,
    const float* __restrict__ W_lih, const float* __restrict__ W_lhh,
    const float* __restrict__ b_lih, const float* __restrict__ b_lhh)
{
  int b = blockIdx.x, d = threadIdx.x;
  const float* qs = q_star + b * 128;
  const float* hp = hl + b * 64;
  float g[4];
#pragma unroll
  for (int gi = 0; gi < 4; ++gi) {
    int row = gi * 64 + d;                    // gate order i, f, g, o
    float a = b_lih[row] + b_lhh[row];
    for (int j = 0; j < 128; ++j) a += qs[j] * W_lih[row * 128 + j];
    for (int j = 0; j < 64; ++j)  a += hp[j] * W_lhh[row * 64 + j];
    g[gi] = a;
  }
  // single wave: all hp[] reads retire before the stores below (lockstep)
  float cv = cl[b * 64 + d];
  cv = sigf(g[1]) * cv + sigf(g[0]) * tanhf(g[2]);
  float hv = sigf(g[3]) * tanhf(cv);
  cl[b * 64 + d] = cv;
  hl[b * 64 + d] = hv;
}

// ------------- Set2Set attention (1 graph / wave; graphs are contiguous 25-node runs)
__global__ __launch_bounds__(64) void k_attn(const float* __restrict__ node_h,
    const float* __restrict__ hl, float* __restrict__ q_star)
{
  int b = blockIdx.x, d = threadIdx.x;
  float qd = hl[b * 64 + d];
  float e_arr[PG];
  float emax = -3.0e38f;
#pragma unroll
  for (int n = 0; n < PG; ++n) {
    float v = node_h[(b * PG + n) * MD + d] * qd;
#pragma unroll
    for (int m = 32; m >= 1; m >>= 1) v += __shfl_xor(v, m, 64);
    e_arr[n] = v;                             // identical across lanes
    emax = fmaxf(emax, v);
  }
  float s = 0.0f, rv = 0.0f;
#pragma unroll
  for (int n = 0; n < PG; ++n) {
    float w = expf(e_arr[n] - emax);
    s += w;
    rv += w * node_h[(b * PG + n) * MD + d];
  }
  rv /= s;
  q_star[b * 128 + d] = qd;
  q_star[b * 128 + 64 + d] = rv;
}

// ------------- head: out = relu(q_star@W_lin1.T+b) @ W_lin2.T + b -------------
__global__ __launch_bounds__(64) void k_final(const float* __restrict__ q_star,
    const float* __restrict__ W_lin1, const float* __restrict__ b_lin1,
    const float* __restrict__ W_lin2, const float* __restrict__ b_lin2,
    float* __restrict__ out)
{
  int b = blockIdx.x, d = threadIdx.x;
  const float* qs = q_star + b * 128;
  float a = b_lin1[d];
  for (int j = 0; j < 128; ++j) a += qs[j] * W_lin1[d * 128 + j];
  a = fmaxf(a, 0.0f);
  float v = a * W_lin2[d];
#pragma unroll
  for (int m = 32; m >= 1; m >>= 1) v += __shfl_xor(v, m, 64);
  if (d == 0) out[b] = v + b_lin2[0];
}

} // namespace

extern "C" void kernel_launch(void* const* d_in, const int* in_sizes, int n_in,
                              void* d_out, int out_size, void* d_ws, size_t ws_size,
                              hipStream_t stream)
{
  const float* x      = (const float*)d_in[0];
  const float* ea     = (const float*)d_in[1];
  const float* W_lin0 = (const float*)d_in[2];
  const float* b_lin0 = (const float*)d_in[3];
  const float* W_h1   = (const float*)d_in[4];
  const float* b_h1   = (const float*)d_in[5];
  const float* W_h2   = (const float*)d_in[6];
  const float* b_h2   = (const float*)d_in[7];
  const float* W_root = (const float*)d_in[8];
  const float* b_conv = (const float*)d_in[9];
  const float* W_ih   = (const float*)d_in[10];
  const float* W_hh   = (const float*)d_in[11];
  const float* b_ih   = (const float*)d_in[12];
  const float* b_hh   = (const float*)d_in[13];
  const float* W_lih  = (const float*)d_in[14];
  const float* W_lhh  = (const float*)d_in[15];
  const float* b_lih  = (const float*)d_in[16];
  const float* b_lhh  = (const float*)d_in[17];
  const float* W_lin1 = (const float*)d_in[18];
  const float* b_lin1 = (const float*)d_in[19];
  const float* W_lin2 = (const float*)d_in[20];
  const float* b_lin2 = (const float*)d_in[21];
  const int*   eidx   = (const int*)d_in[22];
  const int* src = eidx;
  const int* tgt = eidx + NE;
  float* out = (float*)d_out;
  (void)in_sizes; (void)n_in; (void)out_size; (void)ws_size;

  // ---- workspace carve-up (~41 MB total) ----
  char* w = (char*)d_ws;
  size_t off = 0;
  auto take = [&](size_t bytes) -> void* {
    void* p = w + off;
    off += (bytes + 255) & ~(size_t)255;
    return p;
  };
  float* node_h        = (float*)take((size_t)NN * MD * 4);
  __hip_bfloat16* h1   = (__hip_bfloat16*)take((size_t)NE * KH * 2);
  __hip_bfloat16* bpre = (__hip_bfloat16*)take((size_t)524288 * 2);
  float* aggr          = (float*)take((size_t)NN * MD * 4);  // aggr, sx contiguous
  float* sx            = (float*)take((size_t)NN * MD * 4);
  float* inv_deg       = (float*)take((size_t)NN * 4);
  int*   deg_cnt       = (int*)take((size_t)NN * 4);
  float* q_star        = (float*)take((size_t)NB * 128 * 4); // q_star, hl, cl contiguous
  float* hl            = (float*)take((size_t)NB * 64 * 4);
  float* cl            = (float*)take((size_t)NB * 64 * 4);

  hipMemsetAsync(deg_cnt, 0, (size_t)NN * 4, stream);
  k_deg<<<(NE + 255) / 256, 256, 0, stream>>>(tgt, deg_cnt);
  k_invdeg<<<(NN + 255) / 256, 256, 0, stream>>>(deg_cnt, inv_deg);
  k_lin0<<<NN / 4, 256, 0, stream>>>(x, W_lin0, b_lin0, node_h);
  k_h1<<<(NE * KH) / 256, 256, 0, stream>>>(ea, W_h1, b_h1, h1);
  k_pack_b<<<524288 / 256, 256, 0, stream>>>(W_h2, bpre);

  for (int step = 0; step < 3; ++step) {
    hipMemsetAsync(aggr, 0, (size_t)NN * MD * 4 * 2, stream);   // aggr + sx
    k_sx<<<(NE * MD) / 256, 256, 0, stream>>>(src, tgt, node_h, sx);
    k_msg<<<(NE + 127) / 128, 256, 0, stream>>>(h1, bpre, node_h, src, tgt, aggr);
    k_gru<<<NN / 4, 256, 0, stream>>>(node_h, aggr, sx, inv_deg, W_root, b_conv,
                                      b_h2, W_ih, W_hh, b_ih, b_hh);
  }

  hipMemsetAsync(q_star, 0, (size_t)(NB * 128 + NB * 64 + NB * 64) * 4, stream);
  for (int it = 0; it < 3; ++it) {
    k_lstm<<<NB, 64, 0, stream>>>(q_star, hl, cl, W_lih, W_lhh, b_lih, b_lhh);
    k_attn<<<NB, 64, 0, stream>>>(node_h, hl, q_star);
  }
  k_final<<<NB, 64, 0, stream>>>(q_star, W_lin1, b_lin1, W_lin2, b_lin2, out);
}

// Round 2
// 783.359 us; speedup vs baseline: 2.0376x; 2.0376x over previous
//
#include <hip/hip_runtime.h>
#include <hip/hip_bf16.h>

namespace {

constexpr int NN = 30000;   // nodes
constexpr int NE = 60000;   // edges
constexpr int NB = 1200;    // graphs
constexpr int MD = 64;      // DIM
constexpr int FE = 14;      // FEAT
constexpr int PG = 25;      // nodes per graph
constexpr int KH = 128;     // edge-MLP hidden width

typedef __attribute__((ext_vector_type(8))) __bf16 bf16x8;
typedef __attribute__((ext_vector_type(4))) float f32x4;

__device__ __forceinline__ float sigf(float x) { return 1.0f / (1.0f + expf(-x)); }

// ---------------- lin0: node_h = relu(x @ W_lin0.T + b) ----------------
__global__ __launch_bounds__(256) void k_lin0(const float* __restrict__ x,
    const float* __restrict__ W, const float* __restrict__ b,
    float* __restrict__ node_h)
{
  __shared__ float xs[4][FE];
  int tid = threadIdx.x, nl = tid >> 6, d = tid & 63;
  int n = blockIdx.x * 4 + nl;
  if (d < FE) xs[nl][d] = x[n * FE + d];
  __syncthreads();
  float a = b[d];
#pragma unroll
  for (int f = 0; f < FE; ++f) a += xs[nl][f] * W[d * FE + f];
  node_h[n * MD + d] = fmaxf(a, 0.0f);
}

// ---------------- h1 = relu(edge_attr @ W_h1.T + b) -> bf16 ----------------
__global__ __launch_bounds__(256) void k_h1(const float* __restrict__ ea,
    const float* __restrict__ W, const float* __restrict__ b,
    __hip_bfloat16* __restrict__ h1)
{
  int gid = blockIdx.x * 256 + threadIdx.x;   // e*128 + k
  int e = gid >> 7, k = gid & 127;
  const float* a = ea + e * 4;
  float v = b[k] + a[0] * W[k * 4 + 0] + a[1] * W[k * 4 + 1]
                 + a[2] * W[k * 4 + 2] + a[3] * W[k * 4 + 3];
  h1[gid] = __float2bfloat16(fmaxf(v, 0.0f));
}

// ------------- pack W_h2 into MFMA B-fragment order (bf16) -------------
// frag(i, ks, ot): B[k][n] with n = ot*16 + (lane&15), k = ks*32 + (lane>>4)*8 + j
__global__ __launch_bounds__(256) void k_pack_b(const float* __restrict__ W_h2,
    __hip_bfloat16* __restrict__ bpre)
{
  int tid = blockIdx.x * 256 + threadIdx.x;   // < 524288
  int j = tid & 7;
  int l = (tid >> 3) & 63;
  int ot = (tid >> 9) & 3;
  int ks = (tid >> 11) & 3;
  int i = tid >> 13;
  int row = i * MD + ot * 16 + (l & 15);      // W_h2 row = i*64 + o
  int col = ks * 32 + (l >> 4) * 8 + j;       // W_h2 col = k
  bpre[tid] = __float2bfloat16(W_h2[row * KH + col]);
}

// ------------- pack GRU weights j-major: Wcomb[j][g][d], g:0-2 ih(r,z,n) 3-5 hh -------------
__global__ __launch_bounds__(256) void k_pack_w(const float* __restrict__ W_ih,
    const float* __restrict__ W_hh, float* __restrict__ Wc)
{
  int tid = blockIdx.x * 256 + threadIdx.x;   // < 64*384
  int j = tid / 384, r = tid % 384;
  int g = r >> 6, d = r & 63;
  Wc[tid] = (g < 3) ? W_ih[(g * 64 + d) * 64 + j] : W_hh[((g - 3) * 64 + d) * 64 + j];
}

// ------------- pack Set2Set weights j-major -------------
__global__ __launch_bounds__(256) void k_pack_l(const float* __restrict__ W_lih,
    const float* __restrict__ W_lhh, const float* __restrict__ W_lin1,
    float* __restrict__ Lih, float* __restrict__ Lhh, float* __restrict__ L1)
{
  int tid = blockIdx.x * 256 + threadIdx.x;
  if (tid < 128 * 256) {                      // Lih[j*256 + g*64 + d]
    int j = tid >> 8, r = tid & 255, g = r >> 6, d = r & 63;
    Lih[tid] = W_lih[(g * 64 + d) * 128 + j];
  } else if (tid < 128 * 256 + 64 * 256) {    // Lhh[j*256 + g*64 + d]
    int t = tid - 128 * 256;
    int j = t >> 8, r = t & 255, g = r >> 6, d = r & 63;
    Lhh[t] = W_lhh[(g * 64 + d) * 64 + j];
  } else if (tid < 128 * 256 + 64 * 256 + 128 * 64) {  // L1[j*64 + d]
    int t = tid - 128 * 256 - 64 * 256;
    int j = t >> 6, d = t & 63;
    L1[t] = W_lin1[d * 128 + j];
  }
}

// ---------------- degree ----------------
__global__ __launch_bounds__(256) void k_deg(const int* __restrict__ tgt, int* __restrict__ cnt)
{
  int e = blockIdx.x * 256 + threadIdx.x;
  if (e < NE) atomicAdd(&cnt[tgt[e]], 1);
}
__global__ __launch_bounds__(256) void k_invdeg(const int* __restrict__ cnt, float* __restrict__ inv)
{
  int n = blockIdx.x * 256 + threadIdx.x;
  if (n < NN) inv[n] = 1.0f / fmaxf((float)cnt[n], 1.0f);
}

// ------------- message kernel: C[e,o] = sum_i x_e[i] * (h1_e . W_h2[i*64+o,:])
// scatter-added into aggr[tgt[e], o]; also accumulates sx[t,:] += x_src rows.
// 4 waves/block, 32 edges/wave.
__global__ __launch_bounds__(256) void k_msg(
    const __hip_bfloat16* __restrict__ h1,
    const __hip_bfloat16* __restrict__ bpre,
    const float* __restrict__ node_h,
    const int* __restrict__ src,
    const int* __restrict__ tgt,
    float* __restrict__ sx,
    float* __restrict__ aggr)
{
  __shared__ float xT[64 * 132];   // [i][edge], stride 132 (16B-aligned rows)
  __shared__ int s_src[128];
  __shared__ int s_tgt[128];
  const int tid = threadIdx.x;
  const int wid = tid >> 6;
  const int lane = tid & 63;
  const int eb0 = blockIdx.x * 128;

  if (tid < 128) {
    int ge = eb0 + tid;
    s_src[tid] = (ge < NE) ? src[ge] : -1;
    s_tgt[tid] = (ge < NE) ? tgt[ge] : -1;
  }
  __syncthreads();
  for (int idx = tid; idx < 128 * MD; idx += 256) {
    int el = idx >> 6, d = idx & 63;
    int s = s_src[el];
    float v = (s >= 0) ? node_h[s * MD + d] : 0.0f;
    xT[d * 132 + el] = v;
    if (s >= 0) atomicAdd(&sx[s_tgt[el] * MD + d], v);   // fused segment-sum of x_src
  }

  // A fragments: h1 rows (edges). lane: row = lane&15, k = ks*32 + (lane>>4)*8 + j
  const int ew = wid * 32;
  bf16x8 af[2][4];
#pragma unroll
  for (int m = 0; m < 2; ++m) {
    int ge = eb0 + ew + m * 16 + (lane & 15);
    if (ge >= NE) ge = 0;                      // xT row is 0 for OOB -> contribution = 0
    const bf16x8* ap = reinterpret_cast<const bf16x8*>(h1 + (size_t)ge * KH);
#pragma unroll
    for (int ks = 0; ks < 4; ++ks)
      af[m][ks] = ap[ks * 4 + (lane >> 4)];
  }
  __syncthreads();

  const f32x4 z4 = {0.0f, 0.0f, 0.0f, 0.0f};
  f32x4 c[2][4];
#pragma unroll
  for (int m = 0; m < 2; ++m)
#pragma unroll
    for (int ot = 0; ot < 4; ++ot) c[m][ot] = z4;

  const bf16x8* bp = reinterpret_cast<const bf16x8*>(bpre) + lane;

  for (int i = 0; i < MD; ++i) {
    const bf16x8* bpi = bp + (i << 10);
    f32x4 g[2][4];
#pragma unroll
    for (int ks = 0; ks < 4; ++ks) {
      bf16x8 bfr[4];
#pragma unroll
      for (int ot = 0; ot < 4; ++ot)
        bfr[ot] = bpi[((ks * 4 + ot) << 6)];
#pragma unroll
      for (int ot = 0; ot < 4; ++ot)
#pragma unroll
        for (int m = 0; m < 2; ++m)
          g[m][ot] = __builtin_amdgcn_mfma_f32_16x16x32_bf16(
              af[m][ks], bfr[ot], (ks == 0) ? z4 : g[m][ot], 0, 0, 0);
    }
    // C += x_e[i] * G_i  (vectorized: one ds_read_b128 per m, packed f32 FMA)
#pragma unroll
    for (int m = 0; m < 2; ++m) {
      f32x4 xv = *reinterpret_cast<const f32x4*>(
          &xT[i * 132 + ew + m * 16 + ((lane >> 4) << 2)]);
#pragma unroll
      for (int ot = 0; ot < 4; ++ot)
        c[m][ot] += xv * g[m][ot];
    }
  }

  // scatter into aggr[tgt]  (C/D layout: col=lane&15, row=(lane>>4)*4+r)
#pragma unroll
  for (int m = 0; m < 2; ++m)
#pragma unroll
    for (int r = 0; r < 4; ++r) {
      int el = ew + m * 16 + (lane >> 4) * 4 + r;
      int t = s_tgt[el];
      if (t >= 0) {
#pragma unroll
        for (int ot = 0; ot < 4; ++ot)
          atomicAdd(&aggr[t * MD + ot * 16 + (lane & 15)], c[m][ot][r]);
      }
    }
}

// ------------- fused NNConv epilogue + GRU cell (8 nodes/block, coalesced weights) -----
__global__ __launch_bounds__(512) void k_gru(
    float* __restrict__ node_h,
    const float* __restrict__ aggr, const float* __restrict__ sx,
    const float* __restrict__ inv_deg,
    const float* __restrict__ Wc,          // [j][6][64] packed ih|hh
    const float* __restrict__ W_root, const float* __restrict__ b_conv,
    const float* __restrict__ b_h2,
    const float* __restrict__ b_ih, const float* __restrict__ b_hh)
{
  __shared__ float h_s[8][64], sx_s[8][64], m_s[8][64];
  int tid = threadIdx.x, nl = tid >> 6, d = tid & 63;
  int n = blockIdx.x * 8 + nl;
  float hv = node_h[n * MD + d];
  h_s[nl][d] = hv;
  sx_s[nl][d] = sx[n * MD + d];
  __syncthreads();
  // aggr mean incl. b_h2 bias term: (msg_sum + sx @ B2) * inv_deg
  float acc = aggr[n * MD + d];
  float mr = b_conv[d];
#pragma unroll 8
  for (int i = 0; i < 64; ++i) {
    acc += sx_s[nl][i] * b_h2[i * MD + d];     // coalesced
    mr  += h_s[nl][i] * W_root[i * MD + d];    // coalesced
  }
  float mv = fmaxf(acc * inv_deg[n] + mr, 0.0f);
  m_s[nl][d] = mv;
  __syncthreads();
  float gir = b_ih[d], giz = b_ih[64 + d], gin = b_ih[128 + d];
  float ghr = b_hh[d], ghz = b_hh[64 + d], ghn = b_hh[128 + d];
#pragma unroll 8
  for (int j = 0; j < 64; ++j) {
    float mj = m_s[nl][j];
    float hj = h_s[nl][j];
    const float* wj = Wc + j * 384 + d;        // all 6 loads coalesced
    gir += mj * wj[0];
    giz += mj * wj[64];
    gin += mj * wj[128];
    ghr += hj * wj[192];
    ghz += hj * wj[256];
    ghn += hj * wj[320];
  }
  float r = sigf(gir + ghr), z = sigf(giz + ghz);
  float nv = tanhf(gin + r * ghn);
  node_h[n * MD + d] = (1.0f - z) * nv + z * hv;
}

// ------------- fully fused Set2Set (3 iters) + head, one graph per 64-thread block ----
__global__ __launch_bounds__(64) void k_s2s(const float* __restrict__ node_h,
    const float* __restrict__ Lih, const float* __restrict__ Lhh,
    const float* __restrict__ b_lih, const float* __restrict__ b_lhh,
    const float* __restrict__ L1, const float* __restrict__ b_lin1,
    const float* __restrict__ W_lin2, const float* __restrict__ b_lin2,
    float* __restrict__ out)
{
  __shared__ float qs[128];   // q_star = [q | rvec]
  __shared__ float hs[64];
  int b = blockIdx.x, d = threadIdx.x;
  const float* nb = node_h + (size_t)b * PG * MD;
  qs[d] = 0.0f; qs[64 + d] = 0.0f; hs[d] = 0.0f;
  float cl = 0.0f, hl = 0.0f;
  __syncthreads();
  for (int it = 0; it < 3; ++it) {
    // LSTM cell: gates (i,f,g,o) rows g*64+d
    float a0 = b_lih[d] + b_lhh[d];
    float a1 = b_lih[64 + d] + b_lhh[64 + d];
    float a2 = b_lih[128 + d] + b_lhh[128 + d];
    float a3 = b_lih[192 + d] + b_lhh[192 + d];
#pragma unroll 8
    for (int j = 0; j < 128; ++j) {
      float q = qs[j];
      const float* wj = Lih + j * 256 + d;
      a0 += q * wj[0]; a1 += q * wj[64]; a2 += q * wj[128]; a3 += q * wj[192];
    }
#pragma unroll 8
    for (int j = 0; j < 64; ++j) {
      float h = hs[j];
      const float* wj = Lhh + j * 256 + d;
      a0 += h * wj[0]; a1 += h * wj[64]; a2 += h * wj[128]; a3 += h * wj[192];
    }
    cl = sigf(a1) * cl + sigf(a0) * tanhf(a2);
    hl = sigf(a3) * tanhf(cl);
    // attention over this graph's 25 nodes
    float ev[PG];
    float emax = -3.0e38f;
#pragma unroll
    for (int n = 0; n < PG; ++n) {
      float v = nb[n * MD + d] * hl;
#pragma unroll
      for (int m = 32; m >= 1; m >>= 1) v += __shfl_xor(v, m, 64);
      ev[n] = v;
      emax = fmaxf(emax, v);
    }
    float s = 0.0f, rv = 0.0f;
#pragma unroll
    for (int n = 0; n < PG; ++n) {
      float w = expf(ev[n] - emax);
      s += w;
      rv += w * nb[n * MD + d];
    }
    rv /= s;
    __syncthreads();
    hs[d] = hl; qs[d] = hl; qs[64 + d] = rv;
    __syncthreads();
  }
  // head: out = relu(q_star@W_lin1.T+b) @ W_lin2.T + b
  float a = b_lin1[d];
#pragma unroll 8
  for (int j = 0; j < 128; ++j) a += qs[j] * L1[j * 64 + d];
  a = fmaxf(a, 0.0f);
  float v = a * W_lin2[d];
#pragma unroll
  for (int m = 32; m >= 1; m >>= 1) v += __shfl_xor(v, m, 64);
  if (d == 0) out[b] = v + b_lin2[0];
}

} // namespace

extern "C" void kernel_launch(void* const* d_in, const int* in_sizes, int n_in,
                              void* d_out, int out_size, void* d_ws, size_t ws_size,
                              hipStream_t stream)
{
  const float* x      = (const float*)d_in[0];
  const float* ea     = (const float*)d_in[1];
  const float* W_lin0 = (const float*)d_in[2];
  const float* b_lin0 = (const float*)d_in[3];
  const float* W_h1   = (const float*)d_in[4];
  const float* b_h1   = (const float*)d_in[5];
  const float* W_h2   = (const float*)d_in[6];
  const float* b_h2   = (const float*)d_in[7];
  const float* W_root = (const float*)d_in[8];
  const float* b_conv = (const float*)d_in[9];
  const float* W_ih   = (const float*)d_in[10];
  const float* W_hh   = (const float*)d_in[11];
  const float* b_ih   = (const float*)d_in[12];
  const float* b_hh   = (const float*)d_in[13];
  const float* W_lih  = (const float*)d_in[14];
  const float* W_lhh  = (const float*)d_in[15];
  const float* b_lih  = (const float*)d_in[16];
  const float* b_lhh  = (const float*)d_in[17];
  const float* W_lin1 = (const float*)d_in[18];
  const float* b_lin1 = (const float*)d_in[19];
  const float* W_lin2 = (const float*)d_in[20];
  const float* b_lin2 = (const float*)d_in[21];
  const int*   eidx   = (const int*)d_in[22];
  const int* src = eidx;
  const int* tgt = eidx + NE;
  float* out = (float*)d_out;
  (void)in_sizes; (void)n_in; (void)out_size; (void)ws_size;

  // ---- workspace carve-up (~42 MB total) ----
  char* w = (char*)d_ws;
  size_t off = 0;
  auto take = [&](size_t bytes) -> void* {
    void* p = w + off;
    off += (bytes + 255) & ~(size_t)255;
    return p;
  };
  float* node_h        = (float*)take((size_t)NN * MD * 4);
  __hip_bfloat16* h1   = (__hip_bfloat16*)take((size_t)NE * KH * 2);
  __hip_bfloat16* bpre = (__hip_bfloat16*)take((size_t)524288 * 2);
  float* aggr          = (float*)take((size_t)NN * MD * 4);  // aggr, sx contiguous
  float* sx            = (float*)take((size_t)NN * MD * 4);
  float* inv_deg       = (float*)take((size_t)NN * 4);
  int*   deg_cnt       = (int*)take((size_t)NN * 4);
  float* Wcomb         = (float*)take((size_t)64 * 384 * 4);
  float* Lih           = (float*)take((size_t)128 * 256 * 4);
  float* Lhh           = (float*)take((size_t)64 * 256 * 4);
  float* L1            = (float*)take((size_t)128 * 64 * 4);

  hipMemsetAsync(deg_cnt, 0, (size_t)NN * 4, stream);
  k_deg<<<(NE + 255) / 256, 256, 0, stream>>>(tgt, deg_cnt);
  k_invdeg<<<(NN + 255) / 256, 256, 0, stream>>>(deg_cnt, inv_deg);
  k_lin0<<<NN / 4, 256, 0, stream>>>(x, W_lin0, b_lin0, node_h);
  k_h1<<<(NE * KH) / 256, 256, 0, stream>>>(ea, W_h1, b_h1, h1);
  k_pack_b<<<524288 / 256, 256, 0, stream>>>(W_h2, bpre);
  k_pack_w<<<(64 * 384) / 256, 256, 0, stream>>>(W_ih, W_hh, Wcomb);
  k_pack_l<<<(128 * 256 + 64 * 256 + 128 * 64 + 255) / 256, 256, 0, stream>>>(
      W_lih, W_lhh, W_lin1, Lih, Lhh, L1);

  for (int step = 0; step < 3; ++step) {
    hipMemsetAsync(aggr, 0, (size_t)NN * MD * 4 * 2, stream);   // aggr + sx
    k_msg<<<(NE + 127) / 128, 256, 0, stream>>>(h1, bpre, node_h, src, tgt, sx, aggr);
    k_gru<<<NN / 8, 512, 0, stream>>>(node_h, aggr, sx, inv_deg, Wcomb, W_root,
                                      b_conv, b_h2, b_ih, b_hh);
  }

  k_s2s<<<NB, 64, 0, stream>>>(node_h, Lih, Lhh, b_lih, b_lhh, L1, b_lin1,
                               W_lin2, b_lin2, out);
}